// Round 1
// baseline (214.553 us; speedup 1.0000x reference)
//
#include <hip/hip_runtime.h>
#include <hip/hip_bf16.h>

typedef unsigned short u16;
typedef __attribute__((ext_vector_type(8))) short short8v;    // 8 x bf16 (4 VGPR) MFMA A/B frag
typedef __attribute__((ext_vector_type(8))) unsigned short ushort8v;
typedef __attribute__((ext_vector_type(4))) float f32x4;      // MFMA C/D frag

#define GLOBAL_AS __attribute__((address_space(1)))
#define LDS_AS    __attribute__((address_space(3)))

__device__ __forceinline__ void gload_lds16(const void* g, void* l) {
    // 16B/lane direct global->LDS (dest = wave-uniform base + lane*16)
    __builtin_amdgcn_global_load_lds((const GLOBAL_AS unsigned int*)g,
                                     (LDS_AS unsigned int*)l, 16, 0, 0);
}

// ---------------- x: f32 -> bf16 (RNE) ----------------
__global__ __launch_bounds__(256) void conv_x_kernel(const float* __restrict__ X,
                                                     u16* __restrict__ Xb, int n8) {
    int i = blockIdx.x * 256 + threadIdx.x;   // one thread = 8 elements
    if (i >= n8) return;
    const float4* src = (const float4*)X + (size_t)i * 2;
    float4 a = src[0], b = src[1];
    float v[8] = {a.x, a.y, a.z, a.w, b.x, b.y, b.z, b.w};
    ushort8v o;
#pragma unroll
    for (int j = 0; j < 8; ++j) {
        unsigned int u = __builtin_bit_cast(unsigned int, v[j]);
        u += 0x7FFFu + ((u >> 16) & 1u);      // round-to-nearest-even
        o[j] = (u16)(u >> 16);
    }
    *((ushort8v*)Xb + i) = o;
}

// ---------------- W: f32 [K][N] -> sign bf16, transposed to [N][K] ----------------
__global__ __launch_bounds__(256) void conv_w_kernel(const float* __restrict__ W,
                                                     u16* __restrict__ Wt) {
    __shared__ u16 tile[64][72];              // [n_local][k_local], pad 72 for 16B-aligned rows
    const int t  = threadIdx.x;
    const int k0 = (blockIdx.x & 63) * 64;
    const int n0 = (blockIdx.x >> 6) * 64;
#pragma unroll
    for (int i = 0; i < 4; ++i) {
        const int r = i * 16 + (t >> 4);      // k_local
        const int c = (t & 15) * 4;           // n_local
        float4 v = *(const float4*)&W[(size_t)(k0 + r) * 4096 + n0 + c];
        tile[c + 0][r] = (v.x >= 0.f) ? 0x3F80 : 0xBF80;  // +-1.0 bf16
        tile[c + 1][r] = (v.y >= 0.f) ? 0x3F80 : 0xBF80;
        tile[c + 2][r] = (v.z >= 0.f) ? 0x3F80 : 0xBF80;
        tile[c + 3][r] = (v.w >= 0.f) ? 0x3F80 : 0xBF80;
    }
    __syncthreads();
#pragma unroll
    for (int i = 0; i < 2; ++i) {
        const int r = i * 32 + (t >> 3);      // n_local
        const int c = (t & 7) * 8;            // k_local
        ushort8v o;
#pragma unroll
        for (int j = 0; j < 8; ++j) o[j] = tile[r][c + j];
        *(ushort8v*)&Wt[(size_t)(n0 + r) * 4096 + k0 + c] = o;
    }
}

// ---------------- GEMM: C = relu(A[M,K] * Bt[N,K]^T + bias), bf16 in, f32 out ----------------
// m97 structure: 128x128 tile, BK=32, 4 waves (2x2), 4x4 16x16x32 frags/wave,
// global_load_lds width=16 staging, 2 barriers per K-step.
__global__ __launch_bounds__(256) void gemm_bin_kernel(const u16* __restrict__ A,
                                                       const u16* __restrict__ Bt,
                                                       const float* __restrict__ bias,
                                                       float* __restrict__ C) {
    __shared__ u16 As[128 * 32];   // 8 KB, [row][k] rows of 64B
    __shared__ u16 Bs[128 * 32];   // 8 KB

    const int bid = blockIdx.x;
    const int swz = (bid & 7) * 128 + (bid >> 3);   // XCD-aware, bijective (1024 % 8 == 0)
    const int bm  = swz >> 5;                       // 32 tiles each dim
    const int bn  = swz & 31;

    const int tid  = threadIdx.x;
    const int wid  = tid >> 6;
    const int lane = tid & 63;
    const int wr = wid >> 1, wc = wid & 1;          // 2x2 wave grid, each owns 64x64

    // LDS byte offsets of this lane's A/B fragments (A row / B col = lane&15, k-half = lane>>4)
    const int a_off = (wr * 64 + (lane & 15)) * 64 + (lane >> 4) * 16;
    const int b_off = (wc * 64 + (lane & 15)) * 64 + (lane >> 4) * 16;

    // Staging: chunk c = i*4 + wid covers rows c*16..c*16+15; lane covers row c*16+lane/4,
    // k-bytes (lane&3)*16. LDS dest linear => layout [row][k].
    const u16* Asrc = A  + (size_t)(bm * 128 + wid * 16 + (lane >> 2)) * 4096 + (lane & 3) * 8;
    const u16* Bsrc = Bt + (size_t)(bn * 128 + wid * 16 + (lane >> 2)) * 4096 + (lane & 3) * 8;
    char* AsB = (char*)As + wid * 1024;
    char* BsB = (char*)Bs + wid * 1024;

    f32x4 acc[4][4] = {};

    for (int k0 = 0; k0 < 4096; k0 += 32) {
        gload_lds16(Asrc + k0,             AsB);
        gload_lds16(Asrc + 64 * 4096 + k0, AsB + 4096);
        gload_lds16(Bsrc + k0,             BsB);
        gload_lds16(Bsrc + 64 * 4096 + k0, BsB + 4096);
        __syncthreads();   // compiler emits vmcnt(0) drain + barrier

        short8v av[4], bv[4];
#pragma unroll
        for (int m = 0; m < 4; ++m)
            av[m] = *(const short8v*)((const char*)As + a_off + m * 1024);
#pragma unroll
        for (int n = 0; n < 4; ++n)
            bv[n] = *(const short8v*)((const char*)Bs + b_off + n * 1024);
#pragma unroll
        for (int m = 0; m < 4; ++m)
#pragma unroll
            for (int n = 0; n < 4; ++n)
                acc[m][n] = __builtin_amdgcn_mfma_f32_16x16x32_bf16(av[m], bv[n], acc[m][n], 0, 0, 0);
        __syncthreads();   // reads done before next stage overwrites
    }

    // Epilogue: C/D layout col=lane&15, row=(lane>>4)*4+reg (m89-verified)
    const int col0 = bn * 128 + wc * 64 + (lane & 15);
    const int row0 = bm * 128 + wr * 64 + ((lane >> 4) << 2);
#pragma unroll
    for (int n = 0; n < 4; ++n) {
        const float bi = bias[col0 + n * 16];
#pragma unroll
        for (int m = 0; m < 4; ++m) {
#pragma unroll
            for (int r = 0; r < 4; ++r) {
                const float v = acc[m][n][r] + bi;
                C[(size_t)(row0 + m * 16 + r) * 4096 + (col0 + n * 16)] = v > 0.f ? v : 0.f;
            }
        }
    }
}

// ---------------- fallback (only if ws too small): slow but correct ----------------
__global__ __launch_bounds__(256) void fallback_kernel(const float* __restrict__ X,
                                                       const float* __restrict__ W,
                                                       const float* __restrict__ b,
                                                       float* __restrict__ out) {
    __shared__ float xs[16][16];
    __shared__ float ws[16][17];
    const int row = blockIdx.y * 16 + threadIdx.y;
    const int col = blockIdx.x * 16 + threadIdx.x;
    float acc = 0.f;
    for (int k0 = 0; k0 < 4096; k0 += 16) {
        xs[threadIdx.y][threadIdx.x] = X[(size_t)row * 4096 + k0 + threadIdx.x];
        float w = W[(size_t)(k0 + threadIdx.y) * 4096 + col];
        ws[threadIdx.y][threadIdx.x] = (w >= 0.f) ? 1.f : -1.f;
        __syncthreads();
#pragma unroll
        for (int kk = 0; kk < 16; ++kk) acc += xs[threadIdx.y][kk] * ws[kk][threadIdx.x];
        __syncthreads();
    }
    const float v = acc + b[col];
    out[(size_t)row * 4096 + col] = v > 0.f ? v : 0.f;
}

extern "C" void kernel_launch(void* const* d_in, const int* in_sizes, int n_in,
                              void* d_out, int out_size, void* d_ws, size_t ws_size,
                              hipStream_t stream) {
    const float* x = (const float*)d_in[0];
    const float* W = (const float*)d_in[1];
    const float* b = (const float*)d_in[2];
    float* out = (float*)d_out;

    const size_t need = (size_t)2 * 4096 * 4096 * sizeof(u16);   // 64 MB
    if (ws_size < need) {
        fallback_kernel<<<dim3(256, 256), dim3(16, 16), 0, stream>>>(x, W, b, out);
        return;
    }

    u16* Xb = (u16*)d_ws;                       // bf16 x, [4096][4096]
    u16* Wt = Xb + (size_t)4096 * 4096;         // bf16 sign(W)^T, [N][K]

    conv_x_kernel<<<dim3(8192), dim3(256), 0, stream>>>(x, Xb, 4096 * 4096 / 8);
    conv_w_kernel<<<dim3(4096), dim3(256), 0, stream>>>(W, Wt);
    gemm_bin_kernel<<<dim3(1024), dim3(256), 0, stream>>>(Xb, Wt, b, out);
}

// Round 2
// 153.248 us; speedup vs baseline: 1.4000x; 1.4000x over previous
//
#include <hip/hip_runtime.h>
#include <hip/hip_bf16.h>

typedef unsigned short u16;
typedef __attribute__((ext_vector_type(8))) short short8v;    // 8 x bf16 (4 VGPR) MFMA A/B frag
typedef __attribute__((ext_vector_type(8))) unsigned short ushort8v;
typedef __attribute__((ext_vector_type(4))) float f32x4;      // MFMA C/D frag

#define GLOBAL_AS __attribute__((address_space(1)))
#define LDS_AS    __attribute__((address_space(3)))

__device__ __forceinline__ void gload_lds16(const void* g, void* l) {
    // 16B/lane direct global->LDS (dest = wave-uniform base + lane*16)
    __builtin_amdgcn_global_load_lds((const GLOBAL_AS unsigned int*)g,
                                     (LDS_AS unsigned int*)l, 16, 0, 0);
}

// ---------------- x: f32 -> bf16 (RNE) ----------------
__global__ __launch_bounds__(256) void conv_x_kernel(const float* __restrict__ X,
                                                     u16* __restrict__ Xb, int n8) {
    int i = blockIdx.x * 256 + threadIdx.x;   // one thread = 8 elements
    if (i >= n8) return;
    const float4* src = (const float4*)X + (size_t)i * 2;
    float4 a = src[0], b = src[1];
    float v[8] = {a.x, a.y, a.z, a.w, b.x, b.y, b.z, b.w};
    ushort8v o;
#pragma unroll
    for (int j = 0; j < 8; ++j) {
        unsigned int u = __builtin_bit_cast(unsigned int, v[j]);
        u += 0x7FFFu + ((u >> 16) & 1u);      // round-to-nearest-even
        o[j] = (u16)(u >> 16);
    }
    *((ushort8v*)Xb + i) = o;
}

// ---------------- W: f32 [K][N] -> sign bf16, transposed to [N][K] ----------------
__global__ __launch_bounds__(256) void conv_w_kernel(const float* __restrict__ W,
                                                     u16* __restrict__ Wt) {
    __shared__ u16 tile[64][72];              // [n_local][k_local], pad 72 for 16B-aligned rows
    const int t  = threadIdx.x;
    const int k0 = (blockIdx.x & 63) * 64;
    const int n0 = (blockIdx.x >> 6) * 64;
#pragma unroll
    for (int i = 0; i < 4; ++i) {
        const int r = i * 16 + (t >> 4);      // k_local
        const int c = (t & 15) * 4;           // n_local
        float4 v = *(const float4*)&W[(size_t)(k0 + r) * 4096 + n0 + c];
        tile[c + 0][r] = (v.x >= 0.f) ? 0x3F80 : 0xBF80;  // +-1.0 bf16
        tile[c + 1][r] = (v.y >= 0.f) ? 0x3F80 : 0xBF80;
        tile[c + 2][r] = (v.z >= 0.f) ? 0x3F80 : 0xBF80;
        tile[c + 3][r] = (v.w >= 0.f) ? 0x3F80 : 0xBF80;
    }
    __syncthreads();
#pragma unroll
    for (int i = 0; i < 2; ++i) {
        const int r = i * 32 + (t >> 3);      // n_local
        const int c = (t & 7) * 8;            // k_local
        ushort8v o;
#pragma unroll
        for (int j = 0; j < 8; ++j) o[j] = tile[r][c + j];
        *(ushort8v*)&Wt[(size_t)(n0 + r) * 4096 + k0 + c] = o;
    }
}

// ---------------- GEMM: 256x256 tile, BK=64, 8-phase schedule (m201 template) ----------------
// 8 waves (2M x 4N), each owns 128x64 output = acc[8][4] f32x4.
// LDS 128 KiB: buf{0,1} x {A0,A1 | B0,B1} half-regions of 16 KiB (128 rows x 64 bf16).
// st_16x32 swizzle: linear global_load_lds dest + inverse-swizzled global src + XOR'd ds_read.
// Counted vmcnt(4) at phases 4/8 only; raw s_barrier; setprio around MFMA clusters.

#define BAR()        asm volatile("s_barrier" ::: "memory")
#define WAIT_LGKM0() asm volatile("s_waitcnt lgkmcnt(0)" ::: "memory")
#define WAIT_VM4()   asm volatile("s_waitcnt vmcnt(4)" ::: "memory")

// stage one half-tile (128 rows x 64 k): 2 x global_load_lds per thread
#define STAGE_A(bufbase, h, koff)                                                   \
    do {                                                                            \
        const char* _s = Asrc + (size_t)(h) * 1048576 + (koff);                     \
        char* _d = lds + (bufbase) + (h) * 16384 + sldsw;                           \
        gload_lds16(_s, _d);                                                        \
        gload_lds16(_s + 524288, _d + 8192);                                        \
    } while (0)
#define STAGE_B(bufbase, h, koff)                                                   \
    do {                                                                            \
        const char* _s = Bsrc + (size_t)(h) * 1048576 + (koff);                     \
        char* _d = lds + (bufbase) + 32768 + (h) * 16384 + sldsw;                   \
        gload_lds16(_s, _d);                                                        \
        gload_lds16(_s + 524288, _d + 8192);                                        \
    } while (0)

#define LOAD_A(bufbase, mq)                                                         \
    do {                                                                            \
        _Pragma("unroll") for (int mi = 0; mi < 4; ++mi)                            \
        _Pragma("unroll") for (int ks = 0; ks < 2; ++ks)                            \
            af[mi][ks] = *(const short8v*)(lds + (bufbase) + a_rd0 +                \
                                           (mq) * 8192 + mi * 2048 + ks * 64);      \
    } while (0)
#define LOAD_B(bufbase, nq)                                                         \
    do {                                                                            \
        _Pragma("unroll") for (int ni = 0; ni < 2; ++ni)                            \
        _Pragma("unroll") for (int ks = 0; ks < 2; ++ks)                            \
            bf[nq][ni][ks] = *(const short8v*)(lds + (bufbase) + b_rd0 +            \
                                               (nq) * 4096 + ni * 2048 + ks * 64);  \
    } while (0)

#define MFMA_Q(mq, nq)                                                              \
    do {                                                                            \
        __builtin_amdgcn_s_setprio(1);                                              \
        _Pragma("unroll") for (int mi = 0; mi < 4; ++mi)                            \
        _Pragma("unroll") for (int ni = 0; ni < 2; ++ni)                            \
        _Pragma("unroll") for (int ks = 0; ks < 2; ++ks)                            \
            acc[(mq) * 4 + mi][(nq) * 2 + ni] = __builtin_amdgcn_mfma_f32_16x16x32_bf16( \
                af[mi][ks], bf[nq][ni][ks], acc[(mq) * 4 + mi][(nq) * 2 + ni], 0, 0, 0); \
        __builtin_amdgcn_s_setprio(0);                                              \
    } while (0)

__global__ __launch_bounds__(512, 2) void gemm_bin_kernel(const u16* __restrict__ A,
                                                          const u16* __restrict__ Bt,
                                                          const float* __restrict__ bias,
                                                          float* __restrict__ C) {
    __shared__ __attribute__((aligned(1024))) char lds[131072];

    const int bid = blockIdx.x;
    const int swz = (bid & 7) * 32 + (bid >> 3);   // XCD-aware, bijective (256 % 8 == 0)
    const int bm  = swz >> 4;                      // 16x16 tiles
    const int bn  = swz & 15;

    const int tid = threadIdx.x;
    const int w   = tid >> 6;
    const int l   = tid & 63;
    const int wm  = w >> 2;                        // 2 M-waves
    const int wn  = w & 3;                         // 4 N-waves

    // ---- staging addressing (inverse-swizzled global source, linear LDS dest) ----
    // lane covers half-tile row (j*64 + w*8 + (l>>3)); source col-byte pre-permuted so that
    // the linear LDS write lands the st_16x32 layout: col ^= 32 when row bit2 (=l bit5) set.
    const int srow = w * 8 + (l >> 3);
    const int scol = ((l & 7) ^ (((l >> 5) & 1) << 1)) * 16;
    const char* Asrc = (const char*)A  + (size_t)(bm * 256 + srow) * 8192 + scol;
    const char* Bsrc = (const char*)Bt + (size_t)(bn * 256 + srow) * 8192 + scol;
    const int sldsw = w * 1024;

    // ---- ds_read fragment addressing (swizzle folds to a per-thread constant XOR) ----
    // linear = region + row*128 + ks*64 + (l>>4)*16 ; bit9(linear) = bit2(row) = bit2(l&15)
    const int rdcol = (((l >> 4) * 16) ^ (((l >> 2) & 1) << 5));
    const int a_rd0 = wm * 16384 + (l & 15) * 128 + rdcol;                  // + mq*8192 + mi*2048 + ks*64
    const int b_rd0 = 32768 + (wn >> 1) * 16384 + (wn & 1) * 8192
                    + (l & 15) * 128 + rdcol;                               // + nq*4096 + ni*2048 + ks*64

    f32x4  acc[8][4] = {};
    short8v af[4][2];        // current mq subtile: 4 m-frags x 2 k-slices
    short8v bf[2][2][2];     // both nq subtiles alive: [nq][ni][ks]

    // ---- prologue: tile0 all halves + tile1 B halves; wait tile0 landed (leave 4 in flight) ----
    STAGE_A(0, 0, 0);      STAGE_A(0, 1, 0);
    STAGE_B(0, 0, 0);      STAGE_B(0, 1, 0);
    STAGE_B(65536, 0, 128); STAGE_B(65536, 1, 128);
    WAIT_VM4();
    BAR();

    // ---- main loop: 32 iterations x 2 K-tiles (t=2I in buf0, t+1 in buf1) ----
    for (int I = 0; I < 32; ++I) {
        const int koff1 = (2 * I + 1) * 128;          // tile t+1 (A halves, real)
        const int koff2 = ((2 * I + 2) & 63) * 128;   // tile t+2 (wraps to dummy on last iter)
        const int koff3 = ((2 * I + 3) & 63) * 128;   // tile t+3 (dummy on last iter)

        // p1: buf0 quad(0,0); stage A0(t+1)->buf1
        LOAD_A(0, 0); LOAD_B(0, 0);
        STAGE_A(65536, 0, koff1);
        BAR(); WAIT_LGKM0();
        MFMA_Q(0, 0);
        BAR();

        // p2: buf0 quad(0,1); stage A1(t+1)->buf1
        LOAD_B(0, 1);
        STAGE_A(65536, 1, koff1);
        BAR(); WAIT_LGKM0();
        MFMA_Q(0, 1);
        BAR();

        // p3: buf0 quad(1,0); stage B0(t+2)->buf0 (buf0.B free after p2)
        LOAD_A(0, 1);
        STAGE_B(0, 0, koff2);
        BAR(); WAIT_LGKM0();
        MFMA_Q(1, 0);
        BAR();

        // p4: buf0 quad(1,1); stage B1(t+2)->buf0; counted vmcnt
        STAGE_B(0, 1, koff2);
        WAIT_VM4();
        BAR();
        MFMA_Q(1, 1);
        BAR();

        // p5: buf1 quad(0,0); stage A0(t+2)->buf0 (buf0.A free after p3)
        LOAD_A(65536, 0); LOAD_B(65536, 0);
        STAGE_A(0, 0, koff2);
        BAR(); WAIT_LGKM0();
        MFMA_Q(0, 0);
        BAR();

        // p6: buf1 quad(0,1); stage A1(t+2)->buf0
        LOAD_B(65536, 1);
        STAGE_A(0, 1, koff2);
        BAR(); WAIT_LGKM0();
        MFMA_Q(0, 1);
        BAR();

        // p7: buf1 quad(1,0); stage B0(t+3)->buf1 (buf1.B free after p6)
        LOAD_A(65536, 1);
        STAGE_B(65536, 0, koff3);
        BAR(); WAIT_LGKM0();
        MFMA_Q(1, 0);
        BAR();

        // p8: buf1 quad(1,1); stage B1(t+3)->buf1; counted vmcnt
        STAGE_B(65536, 1, koff3);
        WAIT_VM4();
        BAR();
        MFMA_Q(1, 1);
        BAR();
    }
    asm volatile("s_waitcnt vmcnt(0)" ::: "memory");   // drain LDS-DMA before epilogue/endpgm

    // ---- epilogue: bias + ReLU + f32 store (C/D layout: col=l&15, row=(l>>4)*4+r) ----
    const int col0 = bn * 256 + wn * 64 + (l & 15);
    const int row0 = bm * 256 + wm * 128 + ((l >> 4) << 2);
#pragma unroll
    for (int n = 0; n < 4; ++n) {
        const float bi = bias[col0 + n * 16];
#pragma unroll
        for (int m = 0; m < 8; ++m) {
#pragma unroll
            for (int r = 0; r < 4; ++r) {
                const float v = acc[m][n][r] + bi;
                C[(size_t)(row0 + m * 16 + r) * 4096 + (col0 + n * 16)] = v > 0.f ? v : 0.f;
            }
        }
    }
}

// ---------------- fallback (only if ws too small): slow but correct ----------------
__global__ __launch_bounds__(256) void fallback_kernel(const float* __restrict__ X,
                                                       const float* __restrict__ W,
                                                       const float* __restrict__ b,
                                                       float* __restrict__ out) {
    __shared__ float xs[16][16];
    __shared__ float ws[16][17];
    const int row = blockIdx.y * 16 + threadIdx.y;
    const int col = blockIdx.x * 16 + threadIdx.x;
    float acc = 0.f;
    for (int k0 = 0; k0 < 4096; k0 += 16) {
        xs[threadIdx.y][threadIdx.x] = X[(size_t)row * 4096 + k0 + threadIdx.x];
        float w = W[(size_t)(k0 + threadIdx.y) * 4096 + col];
        ws[threadIdx.y][threadIdx.x] = (w >= 0.f) ? 1.f : -1.f;
        __syncthreads();
#pragma unroll
        for (int kk = 0; kk < 16; ++kk) acc += xs[threadIdx.y][kk] * ws[kk][threadIdx.x];
        __syncthreads();
    }
    const float v = acc + b[col];
    out[(size_t)row * 4096 + col] = v > 0.f ? v : 0.f;
}

extern "C" void kernel_launch(void* const* d_in, const int* in_sizes, int n_in,
                              void* d_out, int out_size, void* d_ws, size_t ws_size,
                              hipStream_t stream) {
    const float* x = (const float*)d_in[0];
    const float* W = (const float*)d_in[1];
    const float* b = (const float*)d_in[2];
    float* out = (float*)d_out;

    const size_t need = (size_t)2 * 4096 * 4096 * sizeof(u16);   // 64 MB
    if (ws_size < need) {
        fallback_kernel<<<dim3(256, 256), dim3(16, 16), 0, stream>>>(x, W, b, out);
        return;
    }

    u16* Xb = (u16*)d_ws;                       // bf16 x, [4096][4096]
    u16* Wt = Xb + (size_t)4096 * 4096;         // bf16 sign(W)^T, [N][K]

    conv_x_kernel<<<dim3(8192), dim3(256), 0, stream>>>(x, Xb, 4096 * 4096 / 8);
    conv_w_kernel<<<dim3(4096), dim3(256), 0, stream>>>(W, Wt);
    gemm_bin_kernel<<<dim3(256), dim3(512), 0, stream>>>(Xb, Wt, b, out);
}

// Round 3
// 140.833 us; speedup vs baseline: 1.5235x; 1.0881x over previous
//
#include <hip/hip_runtime.h>
#include <hip/hip_bf16.h>

typedef unsigned short u16;
typedef __attribute__((ext_vector_type(8))) short short8v;    // 8 x bf16 (4 VGPR) MFMA A/B frag
typedef __attribute__((ext_vector_type(8))) unsigned short ushort8v;
typedef __attribute__((ext_vector_type(4))) float f32x4;      // MFMA C/D frag

#define GLOBAL_AS __attribute__((address_space(1)))
#define LDS_AS    __attribute__((address_space(3)))

__device__ __forceinline__ void gload_lds16(const void* g, void* l) {
    // 16B/lane direct global->LDS (dest = wave-uniform base + lane*16)
    __builtin_amdgcn_global_load_lds((const GLOBAL_AS unsigned int*)g,
                                     (LDS_AS unsigned int*)l, 16, 0, 0);
}

// ---------------- x: f32 -> bf16 (RNE) ----------------
__global__ __launch_bounds__(256) void conv_x_kernel(const float* __restrict__ X,
                                                     u16* __restrict__ Xb, int n8) {
    int i = blockIdx.x * 256 + threadIdx.x;   // one thread = 8 elements
    if (i >= n8) return;
    const float4* src = (const float4*)X + (size_t)i * 2;
    float4 a = src[0], b = src[1];
    float v[8] = {a.x, a.y, a.z, a.w, b.x, b.y, b.z, b.w};
    ushort8v o;
#pragma unroll
    for (int j = 0; j < 8; ++j) {
        unsigned int u = __builtin_bit_cast(unsigned int, v[j]);
        u += 0x7FFFu + ((u >> 16) & 1u);      // round-to-nearest-even
        o[j] = (u16)(u >> 16);
    }
    *((ushort8v*)Xb + i) = o;
}

// ---------------- W: f32 [K][N] -> sign bf16, transposed to [N][K] ----------------
__global__ __launch_bounds__(256) void conv_w_kernel(const float* __restrict__ W,
                                                     u16* __restrict__ Wt) {
    __shared__ u16 tile[64][72];              // [n_local][k_local], pad 72 for 16B-aligned rows
    const int t  = threadIdx.x;
    const int k0 = (blockIdx.x & 63) * 64;
    const int n0 = (blockIdx.x >> 6) * 64;
#pragma unroll
    for (int i = 0; i < 4; ++i) {
        const int r = i * 16 + (t >> 4);      // k_local
        const int c = (t & 15) * 4;           // n_local
        float4 v = *(const float4*)&W[(size_t)(k0 + r) * 4096 + n0 + c];
        tile[c + 0][r] = (v.x >= 0.f) ? 0x3F80 : 0xBF80;  // +-1.0 bf16
        tile[c + 1][r] = (v.y >= 0.f) ? 0x3F80 : 0xBF80;
        tile[c + 2][r] = (v.z >= 0.f) ? 0x3F80 : 0xBF80;
        tile[c + 3][r] = (v.w >= 0.f) ? 0x3F80 : 0xBF80;
    }
    __syncthreads();
#pragma unroll
    for (int i = 0; i < 2; ++i) {
        const int r = i * 32 + (t >> 3);      // n_local
        const int c = (t & 7) * 8;            // k_local
        ushort8v o;
#pragma unroll
        for (int j = 0; j < 8; ++j) o[j] = tile[r][c + j];
        *(ushort8v*)&Wt[(size_t)(n0 + r) * 4096 + k0 + c] = o;
    }
}

// ---------------- GEMM: 256x256 tile, BK=64, 8-phase schedule (m201 template) ----------------
// 8 waves (2M x 4N), each owns 128x64 output = acc[8][4] f32x4.
// LDS 128 KiB: buf{0,1} x {A0,A1 | B0,B1} half-regions of 16 KiB (128 rows x 64 bf16).
// 3-bit XOR swizzle (G4 form): colb ^= (row&7)<<4 — spreads the 16-rows-x-4-col fragment
// read across all 8 bank quads per 8-lane phase (conflict-free). Applied as linear
// global_load_lds dest + inverse-permuted global src + XOR'd ds_read col (rule #21).
// Counted vmcnt(4) at phases 4/8 only; raw s_barrier; setprio around MFMA clusters.

#define BAR()        asm volatile("s_barrier" ::: "memory")
#define WAIT_LGKM0() asm volatile("s_waitcnt lgkmcnt(0)" ::: "memory")
#define WAIT_VM4()   asm volatile("s_waitcnt vmcnt(4)" ::: "memory")

// stage one half-tile (128 rows x 64 k): 2 x global_load_lds per thread
#define STAGE_A(bufbase, h, koff)                                                   \
    do {                                                                            \
        const char* _s = Asrc + (size_t)(h) * 1048576 + (koff);                     \
        char* _d = lds + (bufbase) + (h) * 16384 + sldsw;                           \
        gload_lds16(_s, _d);                                                        \
        gload_lds16(_s + 524288, _d + 8192);                                        \
    } while (0)
#define STAGE_B(bufbase, h, koff)                                                   \
    do {                                                                            \
        const char* _s = Bsrc + (size_t)(h) * 1048576 + (koff);                     \
        char* _d = lds + (bufbase) + 32768 + (h) * 16384 + sldsw;                   \
        gload_lds16(_s, _d);                                                        \
        gload_lds16(_s + 524288, _d + 8192);                                        \
    } while (0)

#define LOAD_A(bufbase, mq)                                                         \
    do {                                                                            \
        _Pragma("unroll") for (int mi = 0; mi < 4; ++mi)                            \
        _Pragma("unroll") for (int ks = 0; ks < 2; ++ks)                            \
            af[mi][ks] = *(const short8v*)(lds + (bufbase) + a_rd0 +                \
                                           (mq) * 8192 + mi * 2048 + (rdx ^ (ks * 64))); \
    } while (0)
#define LOAD_B(bufbase, nq)                                                         \
    do {                                                                            \
        _Pragma("unroll") for (int ni = 0; ni < 2; ++ni)                            \
        _Pragma("unroll") for (int ks = 0; ks < 2; ++ks)                            \
            bf[nq][ni][ks] = *(const short8v*)(lds + (bufbase) + b_rd0 +            \
                                               (nq) * 4096 + ni * 2048 + (rdx ^ (ks * 64))); \
    } while (0)

#define MFMA_Q(mq, nq)                                                              \
    do {                                                                            \
        __builtin_amdgcn_s_setprio(1);                                              \
        _Pragma("unroll") for (int mi = 0; mi < 4; ++mi)                            \
        _Pragma("unroll") for (int ni = 0; ni < 2; ++ni)                            \
        _Pragma("unroll") for (int ks = 0; ks < 2; ++ks)                            \
            acc[(mq) * 4 + mi][(nq) * 2 + ni] = __builtin_amdgcn_mfma_f32_16x16x32_bf16( \
                af[mi][ks], bf[nq][ni][ks], acc[(mq) * 4 + mi][(nq) * 2 + ni], 0, 0, 0); \
        __builtin_amdgcn_s_setprio(0);                                              \
    } while (0)

__global__ __launch_bounds__(512, 2) void gemm_bin_kernel(const u16* __restrict__ A,
                                                          const u16* __restrict__ Bt,
                                                          const float* __restrict__ bias,
                                                          float* __restrict__ C) {
    __shared__ __attribute__((aligned(1024))) char lds[131072];

    const int bid = blockIdx.x;
    const int swz = (bid & 7) * 32 + (bid >> 3);   // XCD-aware, bijective (256 % 8 == 0)
    const int bm  = swz >> 4;                      // 16x16 tiles
    const int bn  = swz & 15;

    const int tid = threadIdx.x;
    const int w   = tid >> 6;
    const int l   = tid & 63;
    const int wm  = w >> 2;                        // 2 M-waves
    const int wn  = w & 3;                         // 4 N-waves

    // ---- staging addressing (inverse-permuted global source, linear LDS dest) ----
    // lane writes LDS linear (row = w*8 + l/8, colb = (l&7)*16); target layout holds
    // element (row, colb ^ ((row&7)<<4)), and row&7 == (l>>3)&7 at write time.
    const int srow = w * 8 + (l >> 3);
    const int scol = ((l & 7) ^ ((l >> 3) & 7)) * 16;
    const char* Asrc = (const char*)A  + (size_t)(bm * 256 + srow) * 8192 + scol;
    const char* Bsrc = (const char*)Bt + (size_t)(bn * 256 + srow) * 8192 + scol;
    const int sldsw = w * 1024;

    // ---- ds_read fragment addressing: row = l&15 (+16*mi...), wanted colb = (l>>4)*16 + ks*64.
    // linear colb = wanted ^ ((row&7)<<4); row&7 == l&7, so per-thread constant:
    const int rdx = (((l >> 4) ^ (l & 7)) << 4);   // ks applied as rdx ^ (ks*64) (bit6, no carry)
    const int a_rd0 = wm * 16384 + (l & 15) * 128;                          // + mq*8192 + mi*2048
    const int b_rd0 = 32768 + (wn >> 1) * 16384 + (wn & 1) * 8192
                    + (l & 15) * 128;                                       // + nq*4096 + ni*2048

    f32x4  acc[8][4] = {};
    short8v af[4][2];        // current mq subtile: 4 m-frags x 2 k-slices
    short8v bf[2][2][2];     // both nq subtiles alive: [nq][ni][ks]

    // ---- prologue: tile0 all halves + tile1 B halves; wait tile0 landed (leave 4 in flight) ----
    STAGE_A(0, 0, 0);      STAGE_A(0, 1, 0);
    STAGE_B(0, 0, 0);      STAGE_B(0, 1, 0);
    STAGE_B(65536, 0, 128); STAGE_B(65536, 1, 128);
    WAIT_VM4();
    BAR();

    // ---- main loop: 32 iterations x 2 K-tiles (t=2I in buf0, t+1 in buf1) ----
    for (int I = 0; I < 32; ++I) {
        const int koff1 = (2 * I + 1) * 128;          // tile t+1 (A halves, real)
        const int koff2 = ((2 * I + 2) & 63) * 128;   // tile t+2 (wraps to dummy on last iter)
        const int koff3 = ((2 * I + 3) & 63) * 128;   // tile t+3 (dummy on last iter)

        // p1: buf0 quad(0,0); stage A0(t+1)->buf1
        LOAD_A(0, 0); LOAD_B(0, 0);
        STAGE_A(65536, 0, koff1);
        BAR(); WAIT_LGKM0();
        MFMA_Q(0, 0);
        BAR();

        // p2: buf0 quad(0,1); stage A1(t+1)->buf1
        LOAD_B(0, 1);
        STAGE_A(65536, 1, koff1);
        BAR(); WAIT_LGKM0();
        MFMA_Q(0, 1);
        BAR();

        // p3: buf0 quad(1,0); stage B0(t+2)->buf0 (buf0.B free after p2)
        LOAD_A(0, 1);
        STAGE_B(0, 0, koff2);
        BAR(); WAIT_LGKM0();
        MFMA_Q(1, 0);
        BAR();

        // p4: buf0 quad(1,1); stage B1(t+2)->buf0; counted vmcnt
        STAGE_B(0, 1, koff2);
        WAIT_VM4();
        BAR();
        MFMA_Q(1, 1);
        BAR();

        // p5: buf1 quad(0,0); stage A0(t+2)->buf0 (buf0.A free after p3)
        LOAD_A(65536, 0); LOAD_B(65536, 0);
        STAGE_A(0, 0, koff2);
        BAR(); WAIT_LGKM0();
        MFMA_Q(0, 0);
        BAR();

        // p6: buf1 quad(0,1); stage A1(t+2)->buf0
        LOAD_B(65536, 1);
        STAGE_A(0, 1, koff2);
        BAR(); WAIT_LGKM0();
        MFMA_Q(0, 1);
        BAR();

        // p7: buf1 quad(1,0); stage B0(t+3)->buf1 (buf1.B free after p6)
        LOAD_A(65536, 1);
        STAGE_B(65536, 0, koff3);
        BAR(); WAIT_LGKM0();
        MFMA_Q(1, 0);
        BAR();

        // p8: buf1 quad(1,1); stage B1(t+3)->buf1; counted vmcnt
        STAGE_B(65536, 1, koff3);
        WAIT_VM4();
        BAR();
        MFMA_Q(1, 1);
        BAR();
    }
    asm volatile("s_waitcnt vmcnt(0)" ::: "memory");   // drain LDS-DMA before epilogue/endpgm

    // ---- epilogue: bias + ReLU + f32 store (C/D layout: col=l&15, row=(l>>4)*4+r) ----
    const int col0 = bn * 256 + wn * 64 + (l & 15);
    const int row0 = bm * 256 + wm * 128 + ((l >> 4) << 2);
#pragma unroll
    for (int n = 0; n < 4; ++n) {
        const float bi = bias[col0 + n * 16];
#pragma unroll
        for (int m = 0; m < 8; ++m) {
#pragma unroll
            for (int r = 0; r < 4; ++r) {
                const float v = acc[m][n][r] + bi;
                C[(size_t)(row0 + m * 16 + r) * 4096 + (col0 + n * 16)] = v > 0.f ? v : 0.f;
            }
        }
    }
}

// ---------------- fallback (only if ws too small): slow but correct ----------------
__global__ __launch_bounds__(256) void fallback_kernel(const float* __restrict__ X,
                                                       const float* __restrict__ W,
                                                       const float* __restrict__ b,
                                                       float* __restrict__ out) {
    __shared__ float xs[16][16];
    __shared__ float ws[16][17];
    const int row = blockIdx.y * 16 + threadIdx.y;
    const int col = blockIdx.x * 16 + threadIdx.x;
    float acc = 0.f;
    for (int k0 = 0; k0 < 4096; k0 += 16) {
        xs[threadIdx.y][threadIdx.x] = X[(size_t)row * 4096 + k0 + threadIdx.x];
        float w = W[(size_t)(k0 + threadIdx.y) * 4096 + col];
        ws[threadIdx.y][threadIdx.x] = (w >= 0.f) ? 1.f : -1.f;
        __syncthreads();
#pragma unroll
        for (int kk = 0; kk < 16; ++kk) acc += xs[threadIdx.y][kk] * ws[kk][threadIdx.x];
        __syncthreads();
    }
    const float v = acc + b[col];
    out[(size_t)row * 4096 + col] = v > 0.f ? v : 0.f;
}

extern "C" void kernel_launch(void* const* d_in, const int* in_sizes, int n_in,
                              void* d_out, int out_size, void* d_ws, size_t ws_size,
                              hipStream_t stream) {
    const float* x = (const float*)d_in[0];
    const float* W = (const float*)d_in[1];
    const float* b = (const float*)d_in[2];
    float* out = (float*)d_out;

    const size_t need = (size_t)2 * 4096 * 4096 * sizeof(u16);   // 64 MB
    if (ws_size < need) {
        fallback_kernel<<<dim3(256, 256), dim3(16, 16), 0, stream>>>(x, W, b, out);
        return;
    }

    u16* Xb = (u16*)d_ws;                       // bf16 x, [4096][4096]
    u16* Wt = Xb + (size_t)4096 * 4096;         // bf16 sign(W)^T, [N][K]

    conv_x_kernel<<<dim3(8192), dim3(256), 0, stream>>>(x, Xb, 4096 * 4096 / 8);
    conv_w_kernel<<<dim3(4096), dim3(256), 0, stream>>>(W, Wt);
    gemm_bin_kernel<<<dim3(256), dim3(512), 0, stream>>>(Xb, Wt, b, out);
}